// Round 1
// baseline (1301.264 us; speedup 1.0000x reference)
//
#include <hip/hip_runtime.h>
#include <math.h>

#define NROWS 8192
#define NCOLS 32000
#define KSEL  5734   // int(0.7 * 8192)

// Kernel 1: per-row NLL via single-pass online softmax.
// One block (256 thr) per row; float4 loads (16B/lane coalescing sweet spot).
__global__ __launch_bounds__(256) void row_nll_kernel(
    const float* __restrict__ inp, const int* __restrict__ tgt,
    float* __restrict__ losses)
{
    const int row = blockIdx.x;
    const int tid = threadIdx.x;
    const float4* rp = (const float4*)(inp + (size_t)row * NCOLS);

    float m = -INFINITY;
    float s = 0.0f;
    for (int j = tid; j < NCOLS / 4; j += 256) {
        float4 v = rp[j];
        float cm = fmaxf(fmaxf(v.x, v.y), fmaxf(v.z, v.w));
        if (cm > m) { s *= __expf(m - cm); m = cm; }  // m=-inf first pass: exp(-inf)=0, s stays 0
        s += __expf(v.x - m);
        s += __expf(v.y - m);
        s += __expf(v.z - m);
        s += __expf(v.w - m);
    }

    // wave-level (m,s) combine — every lane has >=31 elems so m is finite
    for (int off = 32; off > 0; off >>= 1) {
        float om = __shfl_down(m, off);
        float os = __shfl_down(s, off);
        float nm = fmaxf(m, om);
        s = s * __expf(m - nm) + os * __expf(om - nm);
        m = nm;
    }

    __shared__ float sm[4], ss[4];
    if ((tid & 63) == 0) { sm[tid >> 6] = m; ss[tid >> 6] = s; }
    __syncthreads();
    if (tid == 0) {
        float M = sm[0], S = ss[0];
        for (int w = 1; w < 4; w++) {
            float om = sm[w], os = ss[w];
            float nm = fmaxf(M, om);
            S = S * __expf(M - nm) + os * __expf(om - nm);
            M = nm;
        }
        float xt = inp[(size_t)row * NCOLS + tgt[row]];  // L2-warm, row just read
        losses[row] = M + __logf(S) - xt;
    }
}

// Kernel 2: exact top-K mean of 8192 positive floats via bitwise radix-select.
// NLL >= 0 so the raw float bit pattern is order-preserving as uint32.
__global__ __launch_bounds__(1024) void topk_mean_kernel(
    const float* __restrict__ losses, float* __restrict__ out)
{
    const int tid = threadIdx.x;
    __shared__ int red_i[16];
    __shared__ float red_f[16];
    __shared__ unsigned int s_prefix;
    __shared__ int s_kk;

    unsigned int key[8];
    float val[8];
#pragma unroll
    for (int i = 0; i < 8; i++) {
        float v = losses[tid + i * 1024];
        val[i] = v;
        key[i] = __float_as_uint(v);
    }
    if (tid == 0) { s_prefix = 0u; s_kk = KSEL; }
    __syncthreads();

    // MSB->LSB radix select of the KSEL-th largest key
    for (int bit = 31; bit >= 0; bit--) {
        const unsigned int cand = s_prefix | (1u << bit);
        const unsigned int mask = ~((1u << bit) - 1u);  // bits [31..bit]
        int c = 0;
#pragma unroll
        for (int i = 0; i < 8; i++) c += (int)((key[i] & mask) == cand);
        for (int off = 32; off > 0; off >>= 1) c += __shfl_down(c, off);
        if ((tid & 63) == 0) red_i[tid >> 6] = c;
        __syncthreads();
        if (tid == 0) {
            int tot = 0;
            for (int w = 0; w < 16; w++) tot += red_i[w];
            if (tot >= s_kk) s_prefix = cand; else s_kk -= tot;
        }
        __syncthreads();
    }

    const unsigned int pivot = s_prefix;  // exact bits of the KSEL-th largest value
    float sum = 0.0f; int cnt = 0;
#pragma unroll
    for (int i = 0; i < 8; i++) {
        if (key[i] > pivot) { sum += val[i]; cnt++; }
    }
    for (int off = 32; off > 0; off >>= 1) {
        sum += __shfl_down(sum, off);
        cnt += __shfl_down(cnt, off);
    }
    if ((tid & 63) == 0) { red_f[tid >> 6] = sum; red_i[tid >> 6] = cnt; }
    __syncthreads();
    if (tid == 0) {
        float ts = 0.0f; int tc = 0;
        for (int w = 0; w < 16; w++) { ts += red_f[w]; tc += red_i[w]; }
        float pv = __uint_as_float(pivot);
        // top-K = all strictly-greater values plus (K - cnt_gt) copies of the pivot value
        out[0] = (ts + (float)(KSEL - tc) * pv) / (float)KSEL;
    }
}

extern "C" void kernel_launch(void* const* d_in, const int* in_sizes, int n_in,
                              void* d_out, int out_size, void* d_ws, size_t ws_size,
                              hipStream_t stream) {
    const float* inp = (const float*)d_in[0];
    const int*   tgt = (const int*)d_in[1];
    float* losses = (float*)d_ws;  // 8192 floats = 32 KB scratch

    row_nll_kernel<<<NROWS, 256, 0, stream>>>(inp, tgt, losses);
    topk_mean_kernel<<<1, 1024, 0, stream>>>(losses, (float*)d_out);
}